// Round 4
// baseline (1221.502 us; speedup 1.0000x reference)
//
#include <hip/hip_runtime.h>
#include <hip/hip_bf16.h>

// MoE (Gemma 8-expert top-2) sparse bf16 MFMA, no-LDS direct-register GEMMs.
// Pipeline: detect -> routing -> transposes (K-major bf16) -> x canonicalize ->
//   gemm_gate (g) -> gemm_up (act = gelu(g)*u, in-place over g) ->
//   gemm_down (unweighted y rows) -> combine (out[t] = w0*y[q0] + w1*y[q1]).
// R4: k-loops have NO __syncthreads / NO LDS: A/B fragments are 16B-contiguous
//     in K-major layout -> global_load_dwordx4 straight to VGPRs with 1-step
//     register double-buffer. Atomics and zero_out eliminated via combine_k.

typedef __attribute__((ext_vector_type(8))) short bf16x8;
typedef __attribute__((ext_vector_type(4))) float f32x4;

static constexpr int T_TOK = 8192;
static constexpr int HID   = 2048;
static constexpr int INTER = 1024;
static constexpr int NEXP  = 8;
static constexpr int NPAIR = T_TOK * 2;            // 16384 (token, slot) pairs
static constexpr int TM    = 128;                  // row tile (pairs)
static constexpr int MAX_ROWS = NPAIR + NEXP * TM; // 17408 padded rows max
static constexpr int MAX_RT   = MAX_ROWS / TM;     // 136 row tiles max

__device__ __forceinline__ unsigned short f2bf(float f) {
  unsigned u = __float_as_uint(f);
  u += 0x7fffu + ((u >> 16) & 1u);   // RNE
  return (unsigned short)(u >> 16);
}
__device__ __forceinline__ float bf2f(unsigned short h) {
  return __uint_as_float(((unsigned)h) << 16);
}

// ----------------------------------------------------------- dtype detect ---
// flag=1: inputs are bf16. flag=0: inputs are fp32.
__global__ void detect_k(const unsigned* __restrict__ xw, int* __restrict__ flagp) {
  int tid = threadIdx.x;   // 64 threads
  int cnt = 0;
  for (int i = tid; i < 256; i += 64) {
    unsigned e = (xw[i] >> 7) & 0xffu;   // exponent of low-half bf16
    cnt += (e >= 0x70u && e <= 0x8fu) ? 1 : 0;
  }
  for (int off = 32; off; off >>= 1) cnt += __shfl_down(cnt, off);
  if (tid == 0) *flagp = (cnt >= 192) ? 1 : 0;
}

// ---------------------------------------------------------------- routing ---
__global__ void routing_k(const int* __restrict__ sel,
                          int* __restrict__ rows, int* __restrict__ posOf,
                          int* __restrict__ offs) {
  __shared__ int cnt[NEXP], cur[NEXP], offs_s[NEXP + 1];
  int tid = threadIdx.x;
  if (tid < NEXP) cnt[tid] = 0;
  __syncthreads();
  for (int p = tid; p < NPAIR; p += 256) atomicAdd(&cnt[sel[p]], 1);
  __syncthreads();
  if (tid == 0) {
    int off = 0;
    for (int e = 0; e < NEXP; ++e) {
      offs_s[e] = off; cur[e] = off;
      off += (cnt[e] + TM - 1) / TM * TM;   // pad each expert to TM rows
    }
    offs_s[NEXP] = off;
  }
  __syncthreads();
  if (tid <= NEXP) offs[tid] = offs_s[tid];
  for (int p = tid; p < NPAIR; p += 256) {
    int e = sel[p];
    int pos = atomicAdd(&cur[e], 1);
    rows[pos] = p >> 1;       // token index
    posOf[p] = pos;           // inverse map for combine
  }
  for (int e = 0; e < NEXP; ++e)
    for (int r = offs_s[e] + cnt[e] + tid; r < offs_s[e + 1]; r += 256)
      rows[r] = 0;            // padding rows: token 0 (never combined)
}

// --------------------------------------------------------- x canonicalize ---
__global__ void convert_x_k(const void* __restrict__ xin,
                            unsigned short* __restrict__ xc,
                            const int* __restrict__ flagp) {
  int flag = *flagp;
  const int nvec = (T_TOK * HID) / 8;
  int v = blockIdx.x * 256 + threadIdx.x;
  int stride = gridDim.x * 256;
  for (; v < nvec; v += stride) {
    if (flag) {
      ((uint4*)xc)[v] = ((const uint4*)xin)[v];
    } else {
      const float4* s = (const float4*)xin;
      float4 a = s[2 * v], b = s[2 * v + 1];
      uint4 o;
      o.x = (unsigned)f2bf(a.x) | ((unsigned)f2bf(a.y) << 16);
      o.y = (unsigned)f2bf(a.z) | ((unsigned)f2bf(a.w) << 16);
      o.z = (unsigned)f2bf(b.x) | ((unsigned)f2bf(b.y) << 16);
      o.w = (unsigned)f2bf(b.z) | ((unsigned)f2bf(b.w) << 16);
      ((uint4*)xc)[v] = o;
    }
  }
}

// -------------------------------------------------------------- transpose ---
// in: [E][R][C] (fp32 or bf16) -> out: [E][C][R] bf16, 64x64 tiles.
__global__ void transpose_k(const void* __restrict__ in,
                            unsigned short* __restrict__ out, int R, int C,
                            const int* __restrict__ flagp) {
  __shared__ unsigned short tile[64][65];
  int flag = *flagp;
  int e = blockIdx.z;
  int c0 = blockIdx.x * 64, r0 = blockIdx.y * 64;
  int tid = threadIdx.x;
  if (flag) {
    const unsigned short* src = (const unsigned short*)in + (size_t)e * R * C;
    int tx = tid & 7, ty = tid >> 3;
#pragma unroll
    for (int i = 0; i < 2; ++i) {
      int rr = ty + i * 32;
      uint4 v = *(const uint4*)(src + (size_t)(r0 + rr) * C + c0 + tx * 8);
      unsigned short* t = &tile[rr][tx * 8];
      t[0] = (unsigned short)v.x; t[1] = (unsigned short)(v.x >> 16);
      t[2] = (unsigned short)v.y; t[3] = (unsigned short)(v.y >> 16);
      t[4] = (unsigned short)v.z; t[5] = (unsigned short)(v.z >> 16);
      t[6] = (unsigned short)v.w; t[7] = (unsigned short)(v.w >> 16);
    }
  } else {
    const float* src = (const float*)in + (size_t)e * R * C;
    int tx = tid & 15, ty = tid >> 4;
#pragma unroll
    for (int i = 0; i < 4; ++i) {
      int rr = ty + i * 16;
      float4 v = *(const float4*)(src + (size_t)(r0 + rr) * C + c0 + tx * 4);
      unsigned short* t = &tile[rr][tx * 4];
      t[0] = f2bf(v.x); t[1] = f2bf(v.y); t[2] = f2bf(v.z); t[3] = f2bf(v.w);
    }
  }
  __syncthreads();
  unsigned short* dst = out + (size_t)e * R * C;
  int tx = tid & 7, ty = tid >> 3;
#pragma unroll
  for (int i = 0; i < 2; ++i) {
    int cc = ty + i * 32;
    unsigned short a0 = tile[tx * 8 + 0][cc], a1 = tile[tx * 8 + 1][cc];
    unsigned short a2 = tile[tx * 8 + 2][cc], a3 = tile[tx * 8 + 3][cc];
    unsigned short a4 = tile[tx * 8 + 4][cc], a5 = tile[tx * 8 + 5][cc];
    unsigned short a6 = tile[tx * 8 + 6][cc], a7 = tile[tx * 8 + 7][cc];
    uint4 v;
    v.x = a0 | ((unsigned)a1 << 16); v.y = a2 | ((unsigned)a3 << 16);
    v.z = a4 | ((unsigned)a5 << 16); v.w = a6 | ((unsigned)a7 << 16);
    *(uint4*)(dst + (size_t)(c0 + cc) * R + r0 + tx * 8) = v;
  }
}

// --------------------------------------------------------------- mfma glue --
__device__ __forceinline__ f32x4 mfma16(bf16x8 a, bf16x8 b, f32x4 c) {
  return __builtin_amdgcn_mfma_f32_16x16x32_bf16(a, b, c, 0, 0, 0);
}

// One GEMM k-loop body, shared by gate/up/down. A gathered rows from `aBase`
// (per-lane row offsets precomputed), B from K-major weight block.
// Tile 128x128, 4 waves (2x2), per-wave 64x64, acc 4x4 f32x4 = 64 regs.
#define GEMM_KLOOP(KDIM, aPtr, bPtr, acc)                                      \
  bf16x8 a0[4], a1[4], b0[4], b1[4];                                           \
  _Pragma("unroll") for (int i = 0; i < 4; ++i)                                \
      a0[i] = *(const bf16x8*)(aPtr + arow[i]);                                \
  _Pragma("unroll") for (int j = 0; j < 4; ++j)                                \
      b0[j] = *(const bf16x8*)(bPtr + brow[j]);                                \
  for (int kk = 0; kk < KDIM; kk += 64) {                                      \
    _Pragma("unroll") for (int i = 0; i < 4; ++i)                              \
        a1[i] = *(const bf16x8*)(aPtr + arow[i] + kk + 32);                    \
    _Pragma("unroll") for (int j = 0; j < 4; ++j)                              \
        b1[j] = *(const bf16x8*)(bPtr + brow[j] + kk + 32);                    \
    _Pragma("unroll") for (int i = 0; i < 4; ++i)                              \
      _Pragma("unroll") for (int j = 0; j < 4; ++j)                            \
          acc[i][j] = mfma16(a0[i], b0[j], acc[i][j]);                         \
    if (kk + 64 < KDIM) {                                                      \
      _Pragma("unroll") for (int i = 0; i < 4; ++i)                            \
          a0[i] = *(const bf16x8*)(aPtr + arow[i] + kk + 64);                  \
      _Pragma("unroll") for (int j = 0; j < 4; ++j)                            \
          b0[j] = *(const bf16x8*)(bPtr + brow[j] + kk + 64);                  \
    }                                                                          \
    _Pragma("unroll") for (int i = 0; i < 4; ++i)                              \
      _Pragma("unroll") for (int j = 0; j < 4; ++j)                            \
          acc[i][j] = mfma16(a1[i], b1[j], acc[i][j]);                         \
  }

// ------------------------------------------------------------- gate GEMM ----
// gact[r][i] = xc[rows[r]] . gwT[e][i]   (bf16 result, pre-activation)
__global__ __launch_bounds__(256, 3) void gemm_gate(
    const unsigned short* __restrict__ xc,
    const unsigned short* __restrict__ gwT,   // [E][INTER][HID]
    const int* __restrict__ rows, const int* __restrict__ offs,
    unsigned short* __restrict__ gact) {
  int nRT = offs[NEXP] >> 7;
  int rowTile = blockIdx.x >> 3;
  if (rowTile >= nRT) return;
  int nt = blockIdx.x & 7;
  int row0 = rowTile << 7;
  int e = 0;
  while (row0 >= offs[e + 1]) ++e;
  int tid = threadIdx.x, wave = tid >> 6, lane = tid & 63;
  int lrow = lane & 15, lquad = lane >> 4;
  int wm = (wave >> 1) << 6, wn = (wave & 1) << 6;

  size_t arow[4], brow[4];
#pragma unroll
  for (int i = 0; i < 4; ++i)
    arow[i] = (size_t)rows[row0 + wm + i * 16 + lrow] * HID + lquad * 8;
  const unsigned short* bB = gwT + ((size_t)e * INTER + (size_t)nt * TM + wn) * HID;
#pragma unroll
  for (int j = 0; j < 4; ++j)
    brow[j] = (size_t)(j * 16 + lrow) * HID + lquad * 8;

  f32x4 acc[4][4] = {};
  GEMM_KLOOP(HID, xc, bB, acc)

  int n0 = nt * TM + wn;
#pragma unroll
  for (int i = 0; i < 4; ++i)
#pragma unroll
    for (int r = 0; r < 4; ++r) {
      int m = row0 + wm + i * 16 + lquad * 4 + r;
      size_t base = (size_t)m * INTER + n0;
#pragma unroll
      for (int j = 0; j < 4; ++j)
        gact[base + j * 16 + lrow] = f2bf(acc[i][j][r]);
    }
}

// --------------------------------------------------------------- up GEMM ----
// gact[r][i] = gelu_tanh(gact[r][i]) * (xc[rows[r]] . uwT[e][i])  (in-place)
__global__ __launch_bounds__(256, 3) void gemm_up(
    const unsigned short* __restrict__ xc,
    const unsigned short* __restrict__ uwT,   // [E][INTER][HID]
    const int* __restrict__ rows, const int* __restrict__ offs,
    unsigned short* gact) {
  int nRT = offs[NEXP] >> 7;
  int rowTile = blockIdx.x >> 3;
  if (rowTile >= nRT) return;
  int nt = blockIdx.x & 7;
  int row0 = rowTile << 7;
  int e = 0;
  while (row0 >= offs[e + 1]) ++e;
  int tid = threadIdx.x, wave = tid >> 6, lane = tid & 63;
  int lrow = lane & 15, lquad = lane >> 4;
  int wm = (wave >> 1) << 6, wn = (wave & 1) << 6;

  size_t arow[4], brow[4];
#pragma unroll
  for (int i = 0; i < 4; ++i)
    arow[i] = (size_t)rows[row0 + wm + i * 16 + lrow] * HID + lquad * 8;
  const unsigned short* bB = uwT + ((size_t)e * INTER + (size_t)nt * TM + wn) * HID;
#pragma unroll
  for (int j = 0; j < 4; ++j)
    brow[j] = (size_t)(j * 16 + lrow) * HID + lquad * 8;

  f32x4 acc[4][4] = {};
  GEMM_KLOOP(HID, xc, bB, acc)

  int n0 = nt * TM + wn;
#pragma unroll
  for (int i = 0; i < 4; ++i)
#pragma unroll
    for (int r = 0; r < 4; ++r) {
      int m = row0 + wm + i * 16 + lquad * 4 + r;
      size_t base = (size_t)m * INTER + n0;
#pragma unroll
      for (int j = 0; j < 4; ++j) {
        float g = bf2f(gact[base + j * 16 + lrow]);
        float u = acc[i][j][r];
        // 0.5*g*(1+tanh(y))*u == g*u*sigmoid(2y), y=0.79788456*(g+0.044715g^3)
        float z = 1.5957691f * (g + 0.044715f * g * g * g);
        float a = g * u / (1.f + __expf(-z));
        gact[base + j * 16 + lrow] = f2bf(a);
      }
    }
}

// ------------------------------------------------------------- down GEMM ----
// y[r][h] = gact[r] . dwT[e][h]   (unweighted; combine applies routing wgts)
__global__ __launch_bounds__(256, 3) void gemm_down(
    const unsigned short* __restrict__ act,   // [MAX_ROWS][INTER] bf16
    const unsigned short* __restrict__ dwT,   // [E][HID][INTER]
    const int* __restrict__ offs,
    unsigned short* __restrict__ y) {         // [MAX_ROWS][HID] bf16
  int nRT = offs[NEXP] >> 7;
  int rowTile = blockIdx.x >> 4;
  if (rowTile >= nRT) return;
  int nt = blockIdx.x & 15;
  int row0 = rowTile << 7;
  int e = 0;
  while (row0 >= offs[e + 1]) ++e;
  int tid = threadIdx.x, wave = tid >> 6, lane = tid & 63;
  int lrow = lane & 15, lquad = lane >> 4;
  int wm = (wave >> 1) << 6, wn = (wave & 1) << 6;

  size_t arow[4], brow[4];
#pragma unroll
  for (int i = 0; i < 4; ++i)
    arow[i] = (size_t)(row0 + wm + i * 16 + lrow) * INTER + lquad * 8;
  const unsigned short* bB = dwT + ((size_t)e * HID + (size_t)nt * TM + wn) * INTER;
#pragma unroll
  for (int j = 0; j < 4; ++j)
    brow[j] = (size_t)(j * 16 + lrow) * INTER + lquad * 8;

  f32x4 acc[4][4] = {};
  GEMM_KLOOP(INTER, act, bB, acc)

  int n0 = nt * TM + wn;
#pragma unroll
  for (int i = 0; i < 4; ++i)
#pragma unroll
    for (int r = 0; r < 4; ++r) {
      int m = row0 + wm + i * 16 + lquad * 4 + r;
      size_t base = (size_t)m * HID + n0;
#pragma unroll
      for (int j = 0; j < 4; ++j)
        y[base + j * 16 + lrow] = f2bf(acc[i][j][r]);
    }
}

// ---------------------------------------------------------------- combine ---
// out[t] = w0 * y[posOf[2t]] + w1 * y[posOf[2t+1]]
__global__ void combine_k(const unsigned short* __restrict__ y,
                          const int* __restrict__ posOf,
                          const void* __restrict__ rwv, void* __restrict__ outv,
                          const int* __restrict__ flagp) {
  int t = blockIdx.x;
  int flag = *flagp;
  float w0, w1;
  if (flag) {
    const unsigned short* rw16 = (const unsigned short*)rwv;
    w0 = bf2f(rw16[2 * t]); w1 = bf2f(rw16[2 * t + 1]);
  } else {
    const float* rwf = (const float*)rwv;
    w0 = rwf[2 * t]; w1 = rwf[2 * t + 1];
  }
  int q0 = posOf[2 * t], q1 = posOf[2 * t + 1];
  const uint4* y0 = (const uint4*)(y + (size_t)q0 * HID);
  const uint4* y1 = (const uint4*)(y + (size_t)q1 * HID);
  int c = threadIdx.x;   // 256 threads x 8 cols = 2048
  uint4 a = y0[c], b = y1[c];
  float o[8];
  o[0] = w0 * bf2f((unsigned short)a.x) + w1 * bf2f((unsigned short)b.x);
  o[1] = w0 * bf2f((unsigned short)(a.x >> 16)) + w1 * bf2f((unsigned short)(b.x >> 16));
  o[2] = w0 * bf2f((unsigned short)a.y) + w1 * bf2f((unsigned short)b.y);
  o[3] = w0 * bf2f((unsigned short)(a.y >> 16)) + w1 * bf2f((unsigned short)(b.y >> 16));
  o[4] = w0 * bf2f((unsigned short)a.z) + w1 * bf2f((unsigned short)b.z);
  o[5] = w0 * bf2f((unsigned short)(a.z >> 16)) + w1 * bf2f((unsigned short)(b.z >> 16));
  o[6] = w0 * bf2f((unsigned short)a.w) + w1 * bf2f((unsigned short)b.w);
  o[7] = w0 * bf2f((unsigned short)(a.w >> 16)) + w1 * bf2f((unsigned short)(b.w >> 16));
  if (flag) {
    uint4 ov;
    ov.x = (unsigned)f2bf(o[0]) | ((unsigned)f2bf(o[1]) << 16);
    ov.y = (unsigned)f2bf(o[2]) | ((unsigned)f2bf(o[3]) << 16);
    ov.z = (unsigned)f2bf(o[4]) | ((unsigned)f2bf(o[5]) << 16);
    ov.w = (unsigned)f2bf(o[6]) | ((unsigned)f2bf(o[7]) << 16);
    ((uint4*)outv)[(size_t)t * (HID / 8) + c] = ov;
  } else {
    float4* of = (float4*)outv + (size_t)t * (HID / 4);
    of[2 * c] = make_float4(o[0], o[1], o[2], o[3]);
    of[2 * c + 1] = make_float4(o[4], o[5], o[6], o[7]);
  }
}

// ------------------------------------------------------------------ launch ---
extern "C" void kernel_launch(void* const* d_in, const int* in_sizes, int n_in,
                              void* d_out, int out_size, void* d_ws, size_t ws_size,
                              hipStream_t stream) {
  (void)in_sizes; (void)n_in; (void)out_size; (void)ws_size;
  const void* x   = d_in[0];
  const int* sel  = (const int*)d_in[1];
  const void* rw  = d_in[2];
  const void* gw  = d_in[3];
  const void* uw  = d_in[4];
  const void* dw  = d_in[5];

  char* ws = (char*)d_ws;
  int* offs  = (int*)ws;                          // ints 0..8
  int* flagp = (int*)(ws + 64);                   // dtype flag
  int* rows  = (int*)(ws + 256);                  // 17408 ints
  int* posOf = (int*)(ws + 256 + MAX_ROWS * 4);   // 16384 ints
  size_t base = 256 + (size_t)MAX_ROWS * 4 + (size_t)NPAIR * 4;  // 135,424 (16B-aligned)
  unsigned short* xc   = (unsigned short*)(ws + base);           // 32 MiB
  unsigned short* gwT  = xc  + (size_t)T_TOK * HID;              // 32 MiB
  unsigned short* uwT  = gwT + (size_t)NEXP * HID * INTER;       // 32 MiB
  unsigned short* dwT  = uwT + (size_t)NEXP * HID * INTER;       // 32 MiB
  unsigned short* gact = dwT + (size_t)NEXP * HID * INTER;       // 34 MiB (g -> act in-place)
  unsigned short* y    = xc;   // aliases xc+gwT+uwT (dead after gemm_up); 68 MiB

  detect_k<<<1, 64, 0, stream>>>((const unsigned*)x, flagp);
  routing_k<<<1, 256, 0, stream>>>(sel, rows, posOf, offs);
  transpose_k<<<dim3(INTER / 64, HID / 64, NEXP), 256, 0, stream>>>(gw, gwT, HID, INTER, flagp);
  transpose_k<<<dim3(INTER / 64, HID / 64, NEXP), 256, 0, stream>>>(uw, uwT, HID, INTER, flagp);
  transpose_k<<<dim3(HID / 64, INTER / 64, NEXP), 256, 0, stream>>>(dw, dwT, INTER, HID, flagp);
  convert_x_k<<<2048, 256, 0, stream>>>(x, xc, flagp);
  gemm_gate<<<MAX_RT * 8, 256, 0, stream>>>(xc, gwT, rows, offs, gact);
  gemm_up<<<MAX_RT * 8, 256, 0, stream>>>(xc, uwT, rows, offs, gact);
  gemm_down<<<MAX_RT * 16, 256, 0, stream>>>(gact, dwT, offs, y);
  combine_k<<<T_TOK, 256, 0, stream>>>(y, posOf, rw, d_out, flagp);
}